// Round 3
// baseline (55367.181 us; speedup 1.0000x reference)
//
#include <hip/hip_runtime.h>
#include <hip/hip_bf16.h>

namespace {

constexpr int NB  = 64;    // batch
constexpr int NN  = 50;    // nodes
constexpr int DM  = 128;   // model dim
constexpr int FFDIM = 512;
constexpr int NHD = 8;     // heads
constexpr int HDM = 16;    // head dim
constexpr int KA  = 15;    // action_k
constexpr int KS  = 35;    // state_k
constexpr int TA  = 16;    // KA+1 tokens (encoder A)
constexpr int TS  = 37;    // KS+2 tokens (encoder S)
constexpr int NT  = 512;   // threads per block
constexpr float BIGF = 1000000000.0f;

constexpr int OFF_H    = 0;
constexpr int OFF_EMBA = TS * DM;                      // 4736
constexpr int OFF_SCR  = OFF_EMBA + TA * DM;           // 6784
constexpr int SCR_FLOATS = 3 * TS * DM + NHD * TS * TS; // 25160
constexpr int SMEM_FLOATS = OFF_SCR + SCR_FLOATS;       // 31944
constexpr int SMEM_BYTES  = SMEM_FLOATS * 4;            // 127776

struct Params {
  const float* x; const int* start;
  const float* a_emb_W; const float* a_emb_b;
  const float* a_attn_W; const float* a_attn_b;
  const float* a_ff_W1; const float* a_ff_b1;
  const float* a_ff_W2; const float* a_ff_b2;
  const float* a_ln;
  const float* s_emb_W; const float* s_emb_b;
  const float* s_attn_W; const float* s_attn_b;
  const float* s_ff_W1; const float* s_ff_b1;
  const float* s_ff_W2; const float* s_ff_b2;
  const float* s_ln;
  const float* WK; const float* bK;
  const float* WV; const float* bV;
  const float* Wq_mlp; const float* bq_mlp;
  const float* d_Wq; const float* d_bq;
  const float* d_Wo; const float* d_bo;
  float* out;   // f32: tours (64x50) ++ logp (64)
};

// out[T x C] = in[T x K] @ W[K x C] + bias, optional relu. in/out in LDS, W/bias global.
// C must be a power-of-two multiple of 4 with NT % (C/4) == 0 (C in {128,256,512}).
__device__ inline void matmul(const float* __restrict__ in, const float* __restrict__ W,
                              const float* __restrict__ bias, float* __restrict__ out,
                              int T, int K, int C, bool relu, int tid)
{
  const int c4 = C >> 2;
  const int cw = tid & (c4 - 1);
  const int g  = tid / c4;
  const int ng = NT / c4;
  const int c  = cw << 2;
#define FMA4_(av, wv4) \
  acc.x = fmaf((av), (wv4).x, acc.x); acc.y = fmaf((av), (wv4).y, acc.y); \
  acc.z = fmaf((av), (wv4).z, acc.z); acc.w = fmaf((av), (wv4).w, acc.w);
  for (int r = g; r < T; r += ng) {
    const float* inr = in + r * K;
    const float* wp  = W + c;
    float4 acc = *(const float4*)(bias + c);
    for (int kk = 0; kk < K; kk += 4) {
      float4 a4 = *(const float4*)(inr + kk);
      float4 w0 = *(const float4*)(wp + (size_t)(kk    ) * C);
      float4 w1 = *(const float4*)(wp + (size_t)(kk + 1) * C);
      float4 w2 = *(const float4*)(wp + (size_t)(kk + 2) * C);
      float4 w3 = *(const float4*)(wp + (size_t)(kk + 3) * C);
      FMA4_(a4.x, w0); FMA4_(a4.y, w1); FMA4_(a4.z, w2); FMA4_(a4.w, w3);
    }
    if (relu) {
      acc.x = fmaxf(acc.x, 0.f); acc.y = fmaxf(acc.y, 0.f);
      acc.z = fmaxf(acc.z, 0.f); acc.w = fmaxf(acc.w, 0.f);
    }
    *(float4*)(out + r * C + c) = acc;
  }
#undef FMA4_
}

// h[r] = LN(h[r] + add[r]) with gamma g, beta bta. One wave per row.
__device__ inline void layernorm_add(float* __restrict__ h, const float* __restrict__ add,
                                     const float* __restrict__ g, const float* __restrict__ bta,
                                     int T, int tid)
{
  const int lane = tid & 63;
  const int wv = tid >> 6;
  for (int r = wv; r < T; r += NT / 64) {
    float v0 = h[r * DM + lane]      + add[r * DM + lane];
    float v1 = h[r * DM + lane + 64] + add[r * DM + lane + 64];
    float sum = v0 + v1;
    for (int off = 32; off; off >>= 1) sum += __shfl_xor(sum, off);
    float mu = sum * (1.0f / 128.0f);
    float d0 = v0 - mu, d1 = v1 - mu;
    float sq = d0 * d0 + d1 * d1;
    for (int off = 32; off; off >>= 1) sq += __shfl_xor(sq, off);
    float rs = 1.0f / sqrtf(sq * (1.0f / 128.0f) + 1e-5f);
    h[r * DM + lane]      = g[lane]      * d0 * rs + bta[lane];
    h[r * DM + lane + 64] = g[lane + 64] * d1 * rs + bta[lane + 64];
  }
}

// 2-layer post-LN transformer encoder. h: T x 128 in LDS, scr: 25160-float LDS scratch.
__device__ void encode_block(float* __restrict__ h, float* __restrict__ scr,
                             const float* __restrict__ tok, int T,
                             const float* __restrict__ embW, const float* __restrict__ embB,
                             const float* __restrict__ attnW, const float* __restrict__ attnB,
                             const float* __restrict__ W1, const float* __restrict__ b1,
                             const float* __restrict__ W2, const float* __restrict__ b2,
                             const float* __restrict__ ln, int tid)
{
  const int lane = tid & 63;
  const int wv = tid >> 6;
  // embedding: h = tok(Tx2) @ embW(2x128) + embB
  for (int idx = tid; idx < T * DM; idx += NT) {
    int r = idx >> 7, c = idx & (DM - 1);
    h[idx] = tok[2 * r] * embW[c] + tok[2 * r + 1] * embW[DM + c] + embB[c];
  }
  __syncthreads();
  float* q = scr;
  float* k = scr + TS * DM;
  float* v = scr + 2 * TS * DM;
  float* s = scr + 3 * TS * DM;
  for (int l = 0; l < 2; ++l) {
    const float* Wq = attnW + (size_t)(l * 4 + 0) * DM * DM;
    const float* Wk = attnW + (size_t)(l * 4 + 1) * DM * DM;
    const float* Wv = attnW + (size_t)(l * 4 + 2) * DM * DM;
    const float* Wo = attnW + (size_t)(l * 4 + 3) * DM * DM;
    const float* bq = attnB + (l * 4 + 0) * DM;
    const float* bk = attnB + (l * 4 + 1) * DM;
    const float* bv = attnB + (l * 4 + 2) * DM;
    const float* bo = attnB + (l * 4 + 3) * DM;
    matmul(h, Wq, bq, q, T, DM, DM, false, tid);
    matmul(h, Wk, bk, k, T, DM, DM, false, tid);
    matmul(h, Wv, bv, v, T, DM, DM, false, tid);
    __syncthreads();
    // scores s[hd][i][j] = (q_i,hd . k_j,hd) / 4
    const int TT = T * T;
    for (int idx = tid; idx < NHD * TT; idx += NT) {
      int hd = idx / TT; int rem = idx - hd * TT; int i = rem / T; int j = rem - i * T;
      const float4* q4 = (const float4*)(q + i * DM + hd * HDM);
      const float4* k4 = (const float4*)(k + j * DM + hd * HDM);
      float acc = 0.f;
#pragma unroll
      for (int d = 0; d < 4; ++d) {
        float4 qa = q4[d], ka = k4[d];
        acc += qa.x * ka.x + qa.y * ka.y + qa.z * ka.z + qa.w * ka.w;
      }
      s[(hd * T + i) * T + j] = acc * 0.25f;
    }
    __syncthreads();
    // row softmax (one wave per (head,row))
    for (int r = wv; r < NHD * T; r += NT / 64) {
      float val = (lane < T) ? s[r * T + lane] : -INFINITY;
      float mx = val;
      for (int off = 32; off; off >>= 1) mx = fmaxf(mx, __shfl_xor(mx, off));
      float e = (lane < T) ? expf(val - mx) : 0.f;
      float sum = e;
      for (int off = 32; off; off >>= 1) sum += __shfl_xor(sum, off);
      if (lane < T) s[r * T + lane] = e / sum;
    }
    __syncthreads();
    // attention output into q (q no longer needed)
    for (int idx = tid; idx < T * DM; idx += NT) {
      int i = idx >> 7, c = idx & (DM - 1); int hd = c >> 4;
      const float* ar = s + (hd * T + i) * T;
      float acc = 0.f;
      for (int j = 0; j < T; ++j) acc = fmaf(ar[j], v[j * DM + c], acc);
      q[idx] = acc;
    }
    __syncthreads();
    // output projection into k, then h = LN(h + proj)
    matmul(q, Wo, bo, k, T, DM, DM, false, tid);
    __syncthreads();
    layernorm_add(h, k, ln + ((l * 2 + 0) * 2 + 0) * DM, ln + ((l * 2 + 0) * 2 + 1) * DM, T, tid);
    __syncthreads();
    // FF: hidden = relu(h@W1+b1) at scr[0..T*512), proj2 at scr+TS*FFDIM
    matmul(h, W1 + (size_t)l * DM * FFDIM, b1 + l * FFDIM, scr, T, DM, FFDIM, true, tid);
    __syncthreads();
    matmul(scr, W2 + (size_t)l * FFDIM * DM, b2 + l * DM, scr + TS * FFDIM, T, FFDIM, DM, false, tid);
    __syncthreads();
    layernorm_add(h, scr + TS * FFDIM, ln + ((l * 2 + 1) * 2 + 0) * DM, ln + ((l * 2 + 1) * 2 + 1) * DM, T, tid);
    __syncthreads();
  }
}

__global__ __launch_bounds__(NT, 1)
void tsp_kernel(Params p)
{
  const int b = blockIdx.x;
  const int tid = threadIdx.x;
  const int lane = tid & 63;
  const int wv = tid >> 6;

  extern __shared__ float sm[];
  float* sh   = sm + OFF_H;     // TS x 128 : current encoder activations
  float* emba = sm + OFF_EMBA;  // TA x 128 : saved encoder-A output
  float* scr  = sm + OFF_SCR;   // 25160-float scratch

  __shared__ float xl[NN * 2];
  __shared__ int   maskS[NN];
  __shared__ int   knnS[KS];
  __shared__ int   validS[KA];
  __shared__ float d2S[NN];
  __shared__ float tokA[TA * 2];
  __shared__ float tokS[TS * 2];
  __shared__ int   lastS;
  __shared__ float logpS;

  // ---- init ----
  for (int i = tid; i < NN * 2; i += NT) xl[i] = p.x[b * NN * 2 + i];
  const int st = p.start[b];
  for (int i = tid; i < NN; i += NT) maskS[i] = (i != st) ? 1 : 0;
  if (tid == 0) {
    lastS = st; logpS = 0.f;
    p.out[b * NN] = (float)st;
  }
  __syncthreads();
  const float fx = xl[2 * st], fy = xl[2 * st + 1];

  for (int t = 0; t < NN - 1; ++t) {
    const int last = lastS;
    const float lx = xl[2 * last], ly = xl[2 * last + 1];

    // ---- squared distances, masked -> BIG (no FMA contraction: match np bit-exact) ----
    for (int j = tid; j < NN; j += NT) {
      float dx = __fsub_rn(xl[2 * j], lx);
      float dy = __fsub_rn(xl[2 * j + 1], ly);
      float dd = __fadd_rn(__fmul_rn(dx, dx), __fmul_rn(dy, dy));
      d2S[j] = maskS[j] ? dd : BIGF;
    }
    __syncthreads();

    // ---- stable top-KS (ascending d2, ties -> lowest index), wave 0 ----
    if (wv == 0) {
      float v = (lane < NN) ? d2S[lane] : 2.0f * BIGF;
      const int vi = lane;
      for (int s2 = 0; s2 < KS; ++s2) {
        float mv = v; int mi = vi;
        for (int off = 32; off; off >>= 1) {
          float ov = __shfl_xor(mv, off);
          int oi = __shfl_xor(mi, off);
          if (ov < mv || (ov == mv && oi < mi)) { mv = ov; mi = oi; }
        }
        if (lane == 0) knnS[s2] = mi;
        if (vi == mi) v = 4.0f * BIGF;  // remove winner
      }
    }
    __syncthreads();

    // ---- valid flags + tokens ----
    if (tid < KA) validS[tid] = maskS[knnS[tid]];
    if (tid < KS) { int j = knnS[tid]; tokS[2 * tid] = xl[2 * j]; tokS[2 * tid + 1] = xl[2 * j + 1]; }
    if (tid < KA) { int j = knnS[tid]; tokA[2 * tid] = xl[2 * j]; tokA[2 * tid + 1] = xl[2 * j + 1]; }
    if (tid == NT - 1) { tokA[2 * KA] = lx; tokA[2 * KA + 1] = ly; }
    if (tid == NT - 2) { tokS[2 * KS] = lx; tokS[2 * KS + 1] = ly; }
    if (tid == NT - 3) { tokS[2 * KS + 2] = fx; tokS[2 * KS + 3] = fy; }
    __syncthreads();

    // ---- encoder A (16 tokens) ----
    encode_block(sh, scr, tokA, TA, p.a_emb_W, p.a_emb_b, p.a_attn_W, p.a_attn_b,
                 p.a_ff_W1, p.a_ff_b1, p.a_ff_W2, p.a_ff_b2, p.a_ln, tid);
    for (int i = tid; i < TA * DM; i += NT) emba[i] = sh[i];
    __syncthreads();

    // ---- encoder S (37 tokens) ----
    encode_block(sh, scr, tokS, TS, p.s_emb_W, p.s_emb_b, p.s_attn_W, p.s_attn_b,
                 p.s_ff_W1, p.s_ff_b1, p.s_ff_W2, p.s_ff_b2, p.s_ln, tid);

    // ---- decoder scratch layout ----
    float* embq = scr;            // 384
    float* embo = scr + 384;      // 15 x 256
    float* Kd   = scr + 4224;     // 15 x 256
    float* Vd   = scr + 8064;     // 15 x 256
    float* hdec = scr + 11904;    // 128
    float* qd   = scr + 12032;    // 128
    float* scd  = scr + 12160;    // 8 x 15 = 120
    float* od   = scr + 12288;    // 128
    float* tmp  = scr + 12416;    // 128

    if (tid < 384) {
      embq[tid] = (tid < 128) ? emba[KA * DM + tid]
                : (tid < 256) ? sh[KS * DM + (tid - 128)]
                              : sh[(KS + 1) * DM + (tid - 256)];
    }
    for (int idx = tid; idx < KA * 256; idx += NT) {
      int r = idx >> 8, c = idx & 255;
      embo[idx] = (c < 128) ? emba[r * DM + c] : sh[r * DM + (c - 128)];
    }
    __syncthreads();

    matmul(embq, p.Wq_mlp, p.bq_mlp, hdec, 1, 384, DM, false, tid);
    matmul(embo, p.WK, p.bK, Kd, KA, 256, 256, false, tid);
    matmul(embo, p.WV, p.bV, Vd, KA, 256, 256, false, tid);
    __syncthreads();

    // ---- decoder layer 0 (cross-attention) ----
    matmul(hdec, p.d_Wq, p.d_bq, qd, 1, DM, DM, false, tid);
    __syncthreads();
    if (tid < NHD * KA) {   // 120 threads (waves 0-1)
      int hd = tid / KA, kk2 = tid - hd * KA;
      const float* qh = qd + hd * HDM;
      const float* kh = Kd + kk2 * 256 + hd * HDM;
      float acc = 0.f;
#pragma unroll
      for (int d = 0; d < HDM; ++d) acc += qh[d] * kh[d];
      acc = acc / 4.0f;
      scd[tid] = validS[kk2] ? acc : -BIGF;
    }
    __syncthreads();
    if (tid < NHD) {
      float mx = -INFINITY;
#pragma unroll
      for (int kk2 = 0; kk2 < KA; ++kk2) mx = fmaxf(mx, scd[tid * KA + kk2]);
      float e[KA]; float sum = 0.f;
#pragma unroll
      for (int kk2 = 0; kk2 < KA; ++kk2) { e[kk2] = expf(scd[tid * KA + kk2] - mx); sum += e[kk2]; }
      float inv = 1.0f / sum;
#pragma unroll
      for (int kk2 = 0; kk2 < KA; ++kk2) scd[tid * KA + kk2] = e[kk2] * inv;
    }
    __syncthreads();
    if (tid < DM) {
      int hd = tid >> 4;
      float acc = 0.f;
#pragma unroll
      for (int kk2 = 0; kk2 < KA; ++kk2) acc = fmaf(scd[hd * KA + kk2], Vd[kk2 * 256 + tid], acc);
      od[tid] = acc;
    }
    __syncthreads();
    matmul(od, p.d_Wo, p.d_bo, tmp, 1, DM, DM, false, tid);
    __syncthreads();
    if (tid < DM) hdec[tid] += tmp[tid];
    __syncthreads();

    // ---- final pointer logits ----
    matmul(hdec, p.d_Wq + DM * DM, p.d_bq + DM, qd, 1, DM, DM, false, tid);
    __syncthreads();
    if (wv == 0) {
      float lg = -BIGF;
      if (lane < KA) {
        const float* kf = Kd + lane * 256 + 128;  // K[:, :, 1]
        float acc = 0.f;
        for (int d = 0; d < DM; ++d) acc = fmaf(qd[d], kf[d], acc);
        acc = acc / 11.313708498984761f;  // sqrt(128)
        lg = validS[lane] ? 10.0f * tanhf(acc) : -BIGF;
      }
      // argmax, ties -> lowest index (== argmax of softmax probs)
      float mv = lg; int mi = (lane < KA) ? lane : 1000;
      for (int off = 32; off; off >>= 1) {
        float ov = __shfl_xor(mv, off);
        int oi = __shfl_xor(mi, off);
        if (ov > mv || (ov == mv && oi < mi)) { mv = ov; mi = oi; }
      }
      float e = (lane < KA) ? expf(lg - mv) : 0.f;
      float sum = e;
      for (int off = 32; off; off >>= 1) sum += __shfl_xor(sum, off);
      if (lane == 0) {
        int nxt = knnS[mi];
        logpS += -logf(sum);  // lg[mi] - mv == 0
        maskS[nxt] = 0;
        lastS = nxt;
        p.out[b * NN + t + 1] = (float)nxt;
      }
    }
    __syncthreads();
  }

  if (tid == 0) p.out[NB * NN + b] = logpS;
}

} // namespace

extern "C" void kernel_launch(void* const* d_in, const int* in_sizes, int n_in,
                              void* d_out, int out_size, void* d_ws, size_t ws_size,
                              hipStream_t stream)
{
  (void)in_sizes; (void)n_in; (void)out_size; (void)d_ws; (void)ws_size;
  Params p;
  p.x        = (const float*)d_in[0];
  p.start    = (const int*)d_in[1];
  // d_in[2]=action_k (15), d_in[3]=state_k (35): fixed by problem, hardcoded.
  p.a_emb_W  = (const float*)d_in[4];
  p.a_emb_b  = (const float*)d_in[5];
  p.a_attn_W = (const float*)d_in[6];
  p.a_attn_b = (const float*)d_in[7];
  p.a_ff_W1  = (const float*)d_in[8];
  p.a_ff_b1  = (const float*)d_in[9];
  p.a_ff_W2  = (const float*)d_in[10];
  p.a_ff_b2  = (const float*)d_in[11];
  p.a_ln     = (const float*)d_in[12];
  p.s_emb_W  = (const float*)d_in[13];
  p.s_emb_b  = (const float*)d_in[14];
  p.s_attn_W = (const float*)d_in[15];
  p.s_attn_b = (const float*)d_in[16];
  p.s_ff_W1  = (const float*)d_in[17];
  p.s_ff_b1  = (const float*)d_in[18];
  p.s_ff_W2  = (const float*)d_in[19];
  p.s_ff_b2  = (const float*)d_in[20];
  p.s_ln     = (const float*)d_in[21];
  p.WK       = (const float*)d_in[22];
  p.bK       = (const float*)d_in[23];
  p.WV       = (const float*)d_in[24];
  p.bV       = (const float*)d_in[25];
  p.Wq_mlp   = (const float*)d_in[26];
  p.bq_mlp   = (const float*)d_in[27];
  p.d_Wq     = (const float*)d_in[28];
  p.d_bq     = (const float*)d_in[29];
  p.d_Wo     = (const float*)d_in[30];
  p.d_bo     = (const float*)d_in[31];
  p.out      = (float*)d_out;

  // 128KB dynamic LDS per workgroup (gfx950 CU has 160KB) — opt in, ignore failure.
  (void)hipFuncSetAttribute((const void*)tsp_kernel,
                            hipFuncAttributeMaxDynamicSharedMemorySize, SMEM_BYTES);
  tsp_kernel<<<NB, NT, SMEM_BYTES, stream>>>(p);
}

// Round 4
// 42286.566 us; speedup vs baseline: 1.3093x; 1.3093x over previous
//
#include <hip/hip_runtime.h>
#include <hip/hip_bf16.h>

namespace {

constexpr int NB  = 64;    // batch
constexpr int NN  = 50;    // nodes
constexpr int DM  = 128;   // model dim
constexpr int FFDIM = 512;
constexpr int NHD = 8;     // heads
constexpr int HDM = 16;    // head dim
constexpr int KA  = 15;    // action_k
constexpr int KS  = 35;    // state_k
constexpr int TA  = 16;    // KA+1 tokens (encoder A)
constexpr int TS  = 37;    // KS+2 tokens (encoder S)
constexpr int NT  = 512;   // threads per block
constexpr float BIGF = 1000000000.0f;

constexpr int OFF_H    = 0;
constexpr int OFF_EMBA = TS * DM;                      // 4736
constexpr int OFF_SCR  = OFF_EMBA + TA * DM;           // 6784
constexpr int SCR_FLOATS = 3 * TS * DM + NHD * TS * TS; // 25160
constexpr int SMEM_FLOATS = OFF_SCR + SCR_FLOATS;       // 31944
constexpr int SMEM_BYTES  = SMEM_FLOATS * 4;            // 127776

struct Params {
  const float* x; const int* start;
  const float* a_emb_W; const float* a_emb_b;
  const float* a_attn_W; const float* a_attn_b;
  const float* a_ff_W1; const float* a_ff_b1;
  const float* a_ff_W2; const float* a_ff_b2;
  const float* a_ln;
  const float* s_emb_W; const float* s_emb_b;
  const float* s_attn_W; const float* s_attn_b;
  const float* s_ff_W1; const float* s_ff_b1;
  const float* s_ff_W2; const float* s_ff_b2;
  const float* s_ln;
  const float* WK; const float* bK;
  const float* WV; const float* bV;
  const float* Wq_mlp; const float* bq_mlp;
  const float* d_Wq; const float* d_bq;
  const float* d_Wo; const float* d_bo;
  float* out;   // f32: tours (64x50) ++ logp (64)
};

// Register-row-tiled matmul: out[T x C] = in[T x K] @ W[K x C] (strides lda/ldw/ldo)
// Each thread owns 4 consecutive columns and R rows -> each weight float4 is
// loaded ONCE per sweep and feeds 16*R FMAs. NT/(C/4)*R should cover T in one sweep.
template<int R>
__device__ inline void matmul_rt(const float* __restrict__ in, int lda,
                                 const float* __restrict__ W, int ldw,
                                 const float* __restrict__ bias,
                                 float* __restrict__ out, int ldo,
                                 int T, int K, int C, bool relu, int tid)
{
  const int c4 = C >> 2;
  const int cw = tid & (c4 - 1);
  const int g  = tid / c4;
  const int ng = NT / c4;
  const int c  = cw << 2;
  const float4 bv = *(const float4*)(bias + c);
#define FMA16_(aa, i) \
  acc[i].x = fmaf((aa).x, w0.x, acc[i].x); acc[i].y = fmaf((aa).x, w0.y, acc[i].y); \
  acc[i].z = fmaf((aa).x, w0.z, acc[i].z); acc[i].w = fmaf((aa).x, w0.w, acc[i].w); \
  acc[i].x = fmaf((aa).y, w1.x, acc[i].x); acc[i].y = fmaf((aa).y, w1.y, acc[i].y); \
  acc[i].z = fmaf((aa).y, w1.z, acc[i].z); acc[i].w = fmaf((aa).y, w1.w, acc[i].w); \
  acc[i].x = fmaf((aa).z, w2.x, acc[i].x); acc[i].y = fmaf((aa).z, w2.y, acc[i].y); \
  acc[i].z = fmaf((aa).z, w2.z, acc[i].z); acc[i].w = fmaf((aa).z, w2.w, acc[i].w); \
  acc[i].x = fmaf((aa).w, w3.x, acc[i].x); acc[i].y = fmaf((aa).w, w3.y, acc[i].y); \
  acc[i].z = fmaf((aa).w, w3.z, acc[i].z); acc[i].w = fmaf((aa).w, w3.w, acc[i].w);
  for (int rb = g * R; rb < T; rb += ng * R) {
    float4 acc[R];
#pragma unroll
    for (int i = 0; i < R; ++i) acc[i] = bv;
    const float* __restrict__ wp = W + c;
    const float* __restrict__ ip = in + rb * lda;
#pragma unroll 2
    for (int kk = 0; kk < K; kk += 4) {
      float4 w0 = *(const float4*)(wp + (size_t)(kk    ) * ldw);
      float4 w1 = *(const float4*)(wp + (size_t)(kk + 1) * ldw);
      float4 w2 = *(const float4*)(wp + (size_t)(kk + 2) * ldw);
      float4 w3 = *(const float4*)(wp + (size_t)(kk + 3) * ldw);
#pragma unroll
      for (int i = 0; i < R; ++i) {
        float4 a = *(const float4*)(ip + i * lda + kk);  // rows >= T read junk; store guarded
        FMA16_(a, i);
      }
    }
#pragma unroll
    for (int i = 0; i < R; ++i) {
      if (rb + i < T) {
        float4 r2 = acc[i];
        if (relu) {
          r2.x = fmaxf(r2.x, 0.f); r2.y = fmaxf(r2.y, 0.f);
          r2.z = fmaxf(r2.z, 0.f); r2.w = fmaxf(r2.w, 0.f);
        }
        *(float4*)(out + (rb + i) * ldo + c) = r2;
      }
    }
  }
#undef FMA16_
}

// out[0..128) = bias + in(1xK) @ W(Kx128). K sliced 4-way across 512 threads,
// LDS-reduced via red[512]. Contains 2 __syncthreads (all threads must call).
__device__ inline void matvec128(const float* __restrict__ in, const float* __restrict__ W,
                                 const float* __restrict__ bias, float* __restrict__ out,
                                 int K, float* __restrict__ red, int tid)
{
  const int c = tid & 127;
  const int s = tid >> 7;
  const int ks = K >> 2;
  const int k0 = s * ks;
  float acc = 0.f;
#pragma unroll 8
  for (int k = k0; k < k0 + ks; ++k) acc = fmaf(in[k], W[(size_t)k * 128 + c], acc);
  red[tid] = acc;
  __syncthreads();
  if (tid < 128) out[c] = bias[c] + ((red[c] + red[128 + c]) + (red[256 + c] + red[384 + c]));
  __syncthreads();
}

// h[r] = LN(h[r] + add[r]) with gamma g, beta bta. One wave per row.
__device__ inline void layernorm_add(float* __restrict__ h, const float* __restrict__ add,
                                     const float* __restrict__ g, const float* __restrict__ bta,
                                     int T, int tid)
{
  const int lane = tid & 63;
  const int wv = tid >> 6;
  for (int r = wv; r < T; r += NT / 64) {
    float v0 = h[r * DM + lane]      + add[r * DM + lane];
    float v1 = h[r * DM + lane + 64] + add[r * DM + lane + 64];
    float sum = v0 + v1;
    for (int off = 32; off; off >>= 1) sum += __shfl_xor(sum, off);
    float mu = sum * (1.0f / 128.0f);
    float d0 = v0 - mu, d1 = v1 - mu;
    float sq = d0 * d0 + d1 * d1;
    for (int off = 32; off; off >>= 1) sq += __shfl_xor(sq, off);
    float rs = 1.0f / sqrtf(sq * (1.0f / 128.0f) + 1e-5f);
    h[r * DM + lane]      = g[lane]      * d0 * rs + bta[lane];
    h[r * DM + lane + 64] = g[lane + 64] * d1 * rs + bta[lane + 64];
  }
}

// 2-layer post-LN transformer encoder. h: T x 128 in LDS, scr: 25160-float LDS scratch.
// RQK: row-tile for C=128 matmuls (covers T in one sweep); RFF: for C=256 col-tiles of FF1.
template<int T, int RQK, int RFF>
__device__ void encode_block(float* __restrict__ h, float* __restrict__ scr,
                             const float* __restrict__ tok,
                             const float* __restrict__ embW, const float* __restrict__ embB,
                             const float* __restrict__ attnW, const float* __restrict__ attnB,
                             const float* __restrict__ W1, const float* __restrict__ b1,
                             const float* __restrict__ W2, const float* __restrict__ b2,
                             const float* __restrict__ ln, int tid)
{
  const int lane = tid & 63;
  const int wv = tid >> 6;
  // embedding: h = tok(Tx2) @ embW(2x128) + embB
  for (int idx = tid; idx < T * DM; idx += NT) {
    int r = idx >> 7, c = idx & (DM - 1);
    h[idx] = tok[2 * r] * embW[c] + tok[2 * r + 1] * embW[DM + c] + embB[c];
  }
  __syncthreads();
  float* q = scr;
  float* k = scr + TS * DM;
  float* v = scr + 2 * TS * DM;
  float* s = scr + 3 * TS * DM;
  for (int l = 0; l < 2; ++l) {
    const float* Wq = attnW + (size_t)(l * 4 + 0) * DM * DM;
    const float* Wk = attnW + (size_t)(l * 4 + 1) * DM * DM;
    const float* Wv = attnW + (size_t)(l * 4 + 2) * DM * DM;
    const float* Wo = attnW + (size_t)(l * 4 + 3) * DM * DM;
    const float* bq = attnB + (l * 4 + 0) * DM;
    const float* bk = attnB + (l * 4 + 1) * DM;
    const float* bv = attnB + (l * 4 + 2) * DM;
    const float* bo = attnB + (l * 4 + 3) * DM;
    matmul_rt<RQK>(h, DM, Wq, DM, bq, q, DM, T, DM, DM, false, tid);
    matmul_rt<RQK>(h, DM, Wk, DM, bk, k, DM, T, DM, DM, false, tid);
    matmul_rt<RQK>(h, DM, Wv, DM, bv, v, DM, T, DM, DM, false, tid);
    __syncthreads();
    // scores s[hd][i][j] = (q_i,hd . k_j,hd) / 4
    constexpr int TT = T * T;
    for (int idx = tid; idx < NHD * TT; idx += NT) {
      int hd = idx / TT; int rem = idx - hd * TT; int i = rem / T; int j = rem - i * T;
      const float4* q4 = (const float4*)(q + i * DM + hd * HDM);
      const float4* k4 = (const float4*)(k + j * DM + hd * HDM);
      float acc = 0.f;
#pragma unroll
      for (int d = 0; d < 4; ++d) {
        float4 qa = q4[d], ka = k4[d];
        acc += qa.x * ka.x + qa.y * ka.y + qa.z * ka.z + qa.w * ka.w;
      }
      s[(hd * T + i) * T + j] = acc * 0.25f;
    }
    __syncthreads();
    // row softmax (one wave per (head,row))
    for (int r = wv; r < NHD * T; r += NT / 64) {
      float val = (lane < T) ? s[r * T + lane] : -INFINITY;
      float mx = val;
      for (int off = 32; off; off >>= 1) mx = fmaxf(mx, __shfl_xor(mx, off));
      float e = (lane < T) ? expf(val - mx) : 0.f;
      float sum = e;
      for (int off = 32; off; off >>= 1) sum += __shfl_xor(sum, off);
      if (lane < T) s[r * T + lane] = e / sum;
    }
    __syncthreads();
    // attention output into q (q no longer needed)
    for (int idx = tid; idx < T * DM; idx += NT) {
      int i = idx >> 7, c = idx & (DM - 1); int hd = c >> 4;
      const float* ar = s + (hd * T + i) * T;
      float acc = 0.f;
#pragma unroll 4
      for (int j = 0; j < T; ++j) acc = fmaf(ar[j], v[j * DM + c], acc);
      q[idx] = acc;
    }
    __syncthreads();
    // output projection into k, then h = LN(h + proj)
    matmul_rt<RQK>(q, DM, Wo, DM, bo, k, DM, T, DM, DM, false, tid);
    __syncthreads();
    layernorm_add(h, k, ln + ((l * 2 + 0) * 2 + 0) * DM, ln + ((l * 2 + 0) * 2 + 1) * DM, T, tid);
    __syncthreads();
    // FF1: two 256-col tiles, each weight half read once; hidden at scr[0..T*512)
    const float* W1l = W1 + (size_t)l * DM * FFDIM;
    const float* b1l = b1 + l * FFDIM;
    matmul_rt<RFF>(h, DM, W1l, FFDIM, b1l, scr, FFDIM, T, DM, 256, true, tid);
    matmul_rt<RFF>(h, DM, W1l + 256, FFDIM, b1l + 256, scr + 256, FFDIM, T, DM, 256, true, tid);
    __syncthreads();
    // FF2
    matmul_rt<RQK>(scr, FFDIM, W2 + (size_t)l * FFDIM * DM, DM, b2 + l * DM,
                   scr + TS * FFDIM, DM, T, FFDIM, DM, false, tid);
    __syncthreads();
    layernorm_add(h, scr + TS * FFDIM, ln + ((l * 2 + 1) * 2 + 0) * DM, ln + ((l * 2 + 1) * 2 + 1) * DM, T, tid);
    __syncthreads();
  }
}

__global__ __launch_bounds__(NT, 1)
void tsp_kernel(Params p)
{
  const int b = blockIdx.x;
  const int tid = threadIdx.x;
  const int lane = tid & 63;
  const int wv = tid >> 6;

  extern __shared__ float sm[];
  float* sh   = sm + OFF_H;     // TS x 128 : current encoder activations
  float* emba = sm + OFF_EMBA;  // TA x 128 : saved encoder-A output
  float* scr  = sm + OFF_SCR;   // 25160-float scratch

  __shared__ float xl[NN * 2];
  __shared__ int   maskS[NN];
  __shared__ int   knnS[KS];
  __shared__ int   validS[KA];
  __shared__ float d2S[NN];
  __shared__ float tokA[TA * 2];
  __shared__ float tokS[TS * 2];
  __shared__ int   lastS;
  __shared__ float logpS;

  // ---- init ----
  for (int i = tid; i < NN * 2; i += NT) xl[i] = p.x[b * NN * 2 + i];
  const int st = p.start[b];
  for (int i = tid; i < NN; i += NT) maskS[i] = (i != st) ? 1 : 0;
  if (tid == 0) {
    lastS = st; logpS = 0.f;
    p.out[b * NN] = (float)st;
  }
  __syncthreads();
  const float fx = xl[2 * st], fy = xl[2 * st + 1];

  for (int t = 0; t < NN - 1; ++t) {
    const int last = lastS;
    const float lx = xl[2 * last], ly = xl[2 * last + 1];

    // ---- squared distances, masked -> BIG (no FMA contraction: match np bit-exact) ----
    for (int j = tid; j < NN; j += NT) {
      float dx = __fsub_rn(xl[2 * j], lx);
      float dy = __fsub_rn(xl[2 * j + 1], ly);
      float dd = __fadd_rn(__fmul_rn(dx, dx), __fmul_rn(dy, dy));
      d2S[j] = maskS[j] ? dd : BIGF;
    }
    __syncthreads();

    // ---- stable top-KS (ascending d2, ties -> lowest index), wave 0 ----
    if (wv == 0) {
      float v = (lane < NN) ? d2S[lane] : 2.0f * BIGF;
      const int vi = lane;
      for (int s2 = 0; s2 < KS; ++s2) {
        float mv = v; int mi = vi;
        for (int off = 32; off; off >>= 1) {
          float ov = __shfl_xor(mv, off);
          int oi = __shfl_xor(mi, off);
          if (ov < mv || (ov == mv && oi < mi)) { mv = ov; mi = oi; }
        }
        if (lane == 0) knnS[s2] = mi;
        if (vi == mi) v = 4.0f * BIGF;  // remove winner
      }
    }
    __syncthreads();

    // ---- valid flags + tokens ----
    if (tid < KA) validS[tid] = maskS[knnS[tid]];
    if (tid < KS) { int j = knnS[tid]; tokS[2 * tid] = xl[2 * j]; tokS[2 * tid + 1] = xl[2 * j + 1]; }
    if (tid < KA) { int j = knnS[tid]; tokA[2 * tid] = xl[2 * j]; tokA[2 * tid + 1] = xl[2 * j + 1]; }
    if (tid == NT - 1) { tokA[2 * KA] = lx; tokA[2 * KA + 1] = ly; }
    if (tid == NT - 2) { tokS[2 * KS] = lx; tokS[2 * KS + 1] = ly; }
    if (tid == NT - 3) { tokS[2 * KS + 2] = fx; tokS[2 * KS + 3] = fy; }
    __syncthreads();

    // ---- encoder A (16 tokens) ----
    encode_block<TA, 1, 2>(sh, scr, tokA, p.a_emb_W, p.a_emb_b, p.a_attn_W, p.a_attn_b,
                           p.a_ff_W1, p.a_ff_b1, p.a_ff_W2, p.a_ff_b2, p.a_ln, tid);
    for (int i = tid; i < TA * DM; i += NT) emba[i] = sh[i];
    __syncthreads();

    // ---- encoder S (37 tokens) ----
    encode_block<TS, 3, 5>(sh, scr, tokS, p.s_emb_W, p.s_emb_b, p.s_attn_W, p.s_attn_b,
                           p.s_ff_W1, p.s_ff_b1, p.s_ff_W2, p.s_ff_b2, p.s_ln, tid);

    // ---- decoder scratch layout ----
    float* embq = scr;            // 384
    float* embo = scr + 384;      // 15 x 256
    float* Kd   = scr + 4224;     // 15 x 256
    float* Vd   = scr + 8064;     // 15 x 256
    float* hdec = scr + 11904;    // 128
    float* qd   = scr + 12032;    // 128
    float* scd  = scr + 12160;    // 8 x 15 = 120
    float* od   = scr + 12288;    // 128
    float* tmp  = scr + 12416;    // 128
    float* red  = scr + 12544;    // 512

    if (tid < 384) {
      embq[tid] = (tid < 128) ? emba[KA * DM + tid]
                : (tid < 256) ? sh[KS * DM + (tid - 128)]
                              : sh[(KS + 1) * DM + (tid - 256)];
    }
    for (int idx = tid; idx < KA * 256; idx += NT) {
      int r = idx >> 8, c = idx & 255;
      embo[idx] = (c < 128) ? emba[r * DM + c] : sh[r * DM + (c - 128)];
    }
    __syncthreads();

    matmul_rt<2>(embo, 256, p.WK, 256, p.bK, Kd, 256, KA, 256, 256, false, tid);
    matmul_rt<2>(embo, 256, p.WV, 256, p.bV, Vd, 256, KA, 256, 256, false, tid);
    matvec128(embq, p.Wq_mlp, p.bq_mlp, hdec, 384, red, tid);  // internal syncs cover KV too

    // ---- decoder layer 0 (cross-attention) ----
    matvec128(hdec, p.d_Wq, p.d_bq, qd, DM, red, tid);
    if (tid < NHD * KA) {   // 120 threads (waves 0-1)
      int hd = tid / KA, kk2 = tid - hd * KA;
      const float* qh = qd + hd * HDM;
      const float* kh = Kd + kk2 * 256 + hd * HDM;
      float acc = 0.f;
#pragma unroll
      for (int d = 0; d < HDM; ++d) acc += qh[d] * kh[d];
      acc = acc / 4.0f;
      scd[tid] = validS[kk2] ? acc : -BIGF;
    }
    __syncthreads();
    if (tid < NHD) {
      float mx = -INFINITY;
#pragma unroll
      for (int kk2 = 0; kk2 < KA; ++kk2) mx = fmaxf(mx, scd[tid * KA + kk2]);
      float e[KA]; float sum = 0.f;
#pragma unroll
      for (int kk2 = 0; kk2 < KA; ++kk2) { e[kk2] = expf(scd[tid * KA + kk2] - mx); sum += e[kk2]; }
      float inv = 1.0f / sum;
#pragma unroll
      for (int kk2 = 0; kk2 < KA; ++kk2) scd[tid * KA + kk2] = e[kk2] * inv;
    }
    __syncthreads();
    if (tid < DM) {
      int hd = tid >> 4;
      float acc = 0.f;
#pragma unroll
      for (int kk2 = 0; kk2 < KA; ++kk2) acc = fmaf(scd[hd * KA + kk2], Vd[kk2 * 256 + tid], acc);
      od[tid] = acc;
    }
    __syncthreads();
    matvec128(od, p.d_Wo, p.d_bo, tmp, DM, red, tid);
    if (tid < DM) hdec[tid] += tmp[tid];
    __syncthreads();

    // ---- final pointer logits ----
    matvec128(hdec, p.d_Wq + DM * DM, p.d_bq + DM, qd, DM, red, tid);
    if (wv == 0) {
      float lg = -BIGF;
      if (lane < KA) {
        const float* kf = Kd + lane * 256 + 128;  // K[:, :, 1]
        float acc = 0.f;
#pragma unroll 8
        for (int d = 0; d < DM; ++d) acc = fmaf(qd[d], kf[d], acc);
        acc = acc / 11.313708498984761f;  // sqrt(128)
        lg = validS[lane] ? 10.0f * tanhf(acc) : -BIGF;
      }
      // argmax, ties -> lowest index (== argmax of softmax probs)
      float mv = lg; int mi = (lane < KA) ? lane : 1000;
      for (int off = 32; off; off >>= 1) {
        float ov = __shfl_xor(mv, off);
        int oi = __shfl_xor(mi, off);
        if (ov > mv || (ov == mv && oi < mi)) { mv = ov; mi = oi; }
      }
      float e = (lane < KA) ? expf(lg - mv) : 0.f;
      float sum = e;
      for (int off = 32; off; off >>= 1) sum += __shfl_xor(sum, off);
      if (lane == 0) {
        int nxt = knnS[mi];
        logpS += -logf(sum);  // lg[mi] - mv == 0
        maskS[nxt] = 0;
        lastS = nxt;
        p.out[b * NN + t + 1] = (float)nxt;
      }
    }
    __syncthreads();
  }

  if (tid == 0) p.out[NB * NN + b] = logpS;
}

} // namespace

extern "C" void kernel_launch(void* const* d_in, const int* in_sizes, int n_in,
                              void* d_out, int out_size, void* d_ws, size_t ws_size,
                              hipStream_t stream)
{
  (void)in_sizes; (void)n_in; (void)out_size; (void)d_ws; (void)ws_size;
  Params p;
  p.x        = (const float*)d_in[0];
  p.start    = (const int*)d_in[1];
  // d_in[2]=action_k (15), d_in[3]=state_k (35): fixed by problem, hardcoded.
  p.a_emb_W  = (const float*)d_in[4];
  p.a_emb_b  = (const float*)d_in[5];
  p.a_attn_W = (const float*)d_in[6];
  p.a_attn_b = (const float*)d_in[7];
  p.a_ff_W1  = (const float*)d_in[8];
  p.a_ff_b1  = (const float*)d_in[9];
  p.a_ff_W2  = (const float*)d_in[10];
  p.a_ff_b2  = (const float*)d_in[11];
  p.a_ln     = (const float*)d_in[12];
  p.s_emb_W  = (const float*)d_in[13];
  p.s_emb_b  = (const float*)d_in[14];
  p.s_attn_W = (const float*)d_in[15];
  p.s_attn_b = (const float*)d_in[16];
  p.s_ff_W1  = (const float*)d_in[17];
  p.s_ff_b1  = (const float*)d_in[18];
  p.s_ff_W2  = (const float*)d_in[19];
  p.s_ff_b2  = (const float*)d_in[20];
  p.s_ln     = (const float*)d_in[21];
  p.WK       = (const float*)d_in[22];
  p.bK       = (const float*)d_in[23];
  p.WV       = (const float*)d_in[24];
  p.bV       = (const float*)d_in[25];
  p.Wq_mlp   = (const float*)d_in[26];
  p.bq_mlp   = (const float*)d_in[27];
  p.d_Wq     = (const float*)d_in[28];
  p.d_bq     = (const float*)d_in[29];
  p.d_Wo     = (const float*)d_in[30];
  p.d_bo     = (const float*)d_in[31];
  p.out      = (float*)d_out;

  // 128KB dynamic LDS per workgroup (gfx950 CU has 160KB) — opt in, ignore failure.
  (void)hipFuncSetAttribute((const void*)tsp_kernel,
                            hipFuncAttributeMaxDynamicSharedMemorySize, SMEM_BYTES);
  tsp_kernel<<<NB, NT, SMEM_BYTES, stream>>>(p);
}

// Round 5
// 41794.144 us; speedup vs baseline: 1.3248x; 1.0118x over previous
//
#include <hip/hip_runtime.h>

namespace {

constexpr int NB  = 64;    // batch
constexpr int NN  = 50;    // nodes
constexpr int DM  = 128;   // model dim
constexpr int FFDIM = 512;
constexpr int NHD = 8;     // heads
constexpr int HDM = 16;    // head dim
constexpr int KA  = 15;    // action_k
constexpr int KS  = 35;    // state_k
constexpr int TA  = 16;    // KA+1 tokens (encoder A)
constexpr int TS  = 37;    // KS+2 tokens (encoder S)
constexpr int NT  = 1024;  // threads per block: waves 0-3 -> encoder A, waves 4-15 -> encoder S
constexpr float BIGF = 1000000000.0f;

// dynamic LDS layout (floats)
constexpr int OFF_HA   = 0;                 // 16*128  = 2048
constexpr int OFF_SCRA = 2048;              // A scratch: max(3*16*128 + 4*16*16, 16*256+16*128) = 7168
constexpr int OFF_HS   = 9216;              // 37*128 = 4736
constexpr int OFF_SCRS = 13952;             // S scratch: max(3*37*128 + 4*37*37, 37*256+37*128) = 19684 -> 19712
constexpr int SMEM_FLOATS = 33664;
constexpr int SMEM_BYTES  = SMEM_FLOATS * 4;  // 134656 B (<160KB)

struct Params {
  const float* x; const int* start;
  const float* a_emb_W; const float* a_emb_b;
  const float* a_attn_W; const float* a_attn_b;
  const float* a_ff_W1; const float* a_ff_b1;
  const float* a_ff_W2; const float* a_ff_b2;
  const float* a_ln;
  const float* s_emb_W; const float* s_emb_b;
  const float* s_attn_W; const float* s_attn_b;
  const float* s_ff_W1; const float* s_ff_b1;
  const float* s_ff_W2; const float* s_ff_b2;
  const float* s_ln;
  const float* WK; const float* bK;
  const float* WV; const float* bV;
  const float* Wq_mlp; const float* bq_mlp;
  const float* d_Wq; const float* d_bq;
  const float* d_Wo; const float* d_bo;
  float* out;   // f32: tours (64x50) ++ logp (64)
};

// Register-row-tiled matmul over a thread-subset [0,nth): out[T x C] = in[T x K] @ W[K x C].
// C, K compile-time (C in {128,256} pow2). Each thread owns 4 cols x R rows; weight
// float4 loaded once feeds 16*R FMAs. Junk-row loads land in adjacent LDS (allocated);
// stores are guarded. accum=true: initialize acc from existing out instead of bias.
template<int R, int C, int K>
__device__ inline void matmul_rt(const float* __restrict__ in, int lda,
                                 const float* __restrict__ W, int ldw,
                                 const float* __restrict__ bias,
                                 float* __restrict__ out, int ldo,
                                 int T, bool relu, bool accum,
                                 int tid, int nth)
{
  constexpr int c4 = C >> 2;
  const int cw = tid & (c4 - 1);
  const int g  = tid / c4;          // c4 compile-time pow2 -> shift
  const int ng = nth / c4;
  const int c  = cw << 2;
#define FMA16_(aa, i) \
  acc[i].x = fmaf((aa).x, w0.x, acc[i].x); acc[i].y = fmaf((aa).x, w0.y, acc[i].y); \
  acc[i].z = fmaf((aa).x, w0.z, acc[i].z); acc[i].w = fmaf((aa).x, w0.w, acc[i].w); \
  acc[i].x = fmaf((aa).y, w1.x, acc[i].x); acc[i].y = fmaf((aa).y, w1.y, acc[i].y); \
  acc[i].z = fmaf((aa).y, w1.z, acc[i].z); acc[i].w = fmaf((aa).y, w1.w, acc[i].w); \
  acc[i].x = fmaf((aa).z, w2.x, acc[i].x); acc[i].y = fmaf((aa).z, w2.y, acc[i].y); \
  acc[i].z = fmaf((aa).z, w2.z, acc[i].z); acc[i].w = fmaf((aa).z, w2.w, acc[i].w); \
  acc[i].x = fmaf((aa).w, w3.x, acc[i].x); acc[i].y = fmaf((aa).w, w3.y, acc[i].y); \
  acc[i].z = fmaf((aa).w, w3.z, acc[i].z); acc[i].w = fmaf((aa).w, w3.w, acc[i].w);
  for (int rb = g * R; rb < T; rb += ng * R) {
    float4 acc[R];
    if (accum) {
#pragma unroll
      for (int i = 0; i < R; ++i) acc[i] = *(const float4*)(out + (rb + i) * ldo + c);
    } else {
      const float4 bv = *(const float4*)(bias + c);
#pragma unroll
      for (int i = 0; i < R; ++i) acc[i] = bv;
    }
    const float* __restrict__ wp = W + c;
    const float* __restrict__ ip = in + rb * lda;
#pragma unroll 2
    for (int kk = 0; kk < K; kk += 4) {
      float4 w0 = *(const float4*)(wp + (size_t)(kk    ) * ldw);
      float4 w1 = *(const float4*)(wp + (size_t)(kk + 1) * ldw);
      float4 w2 = *(const float4*)(wp + (size_t)(kk + 2) * ldw);
      float4 w3 = *(const float4*)(wp + (size_t)(kk + 3) * ldw);
#pragma unroll
      for (int i = 0; i < R; ++i) {
        float4 a = *(const float4*)(ip + i * lda + kk);
        FMA16_(a, i);
      }
    }
#pragma unroll
    for (int i = 0; i < R; ++i) {
      if (rb + i < T) {
        float4 r2 = acc[i];
        if (relu) {
          r2.x = fmaxf(r2.x, 0.f); r2.y = fmaxf(r2.y, 0.f);
          r2.z = fmaxf(r2.z, 0.f); r2.w = fmaxf(r2.w, 0.f);
        }
        *(float4*)(out + (rb + i) * ldo + c) = r2;
      }
    }
  }
#undef FMA16_
}

// out[0..128) = bias + in(1xK) @ W(Kx128). K sliced 8-way across 1024 threads,
// LDS-reduced via red[1024]. Contains 2 __syncthreads (all 1024 threads must call).
__device__ inline void matvec128(const float* __restrict__ in, const float* __restrict__ W,
                                 const float* __restrict__ bias, float* __restrict__ out,
                                 int K, float* __restrict__ red, int tid)
{
  const int c = tid & 127;
  const int s = tid >> 7;      // 0..7
  const int ks = K >> 3;
  const int k0 = s * ks;
  float acc = 0.f;
#pragma unroll 8
  for (int k = k0; k < k0 + ks; ++k) acc = fmaf(in[k], W[(size_t)k * 128 + c], acc);
  red[tid] = acc;
  __syncthreads();
  if (tid < 128) {
    float sum = ((red[c] + red[128 + c]) + (red[256 + c] + red[384 + c]))
              + ((red[512 + c] + red[640 + c]) + (red[768 + c] + red[896 + c]));
    out[c] = bias[c] + sum;
  }
  __syncthreads();
}

// h[r] = LN(h[r] + add[r]). One wave per row within the nth-thread subset.
__device__ inline void layernorm_add(float* __restrict__ h, const float* __restrict__ add,
                                     const float* __restrict__ g, const float* __restrict__ bta,
                                     int T, int tid, int nth)
{
  const int lane = tid & 63;
  const int wvl = tid >> 6;
  const int nwv = nth >> 6;
  for (int r = wvl; r < T; r += nwv) {
    float v0 = h[r * DM + lane]      + add[r * DM + lane];
    float v1 = h[r * DM + lane + 64] + add[r * DM + lane + 64];
    float sum = v0 + v1;
    for (int off = 32; off; off >>= 1) sum += __shfl_xor(sum, off);
    float mu = sum * (1.0f / 128.0f);
    float d0 = v0 - mu, d1 = v1 - mu;
    float sq = d0 * d0 + d1 * d1;
    for (int off = 32; off; off >>= 1) sq += __shfl_xor(sq, off);
    float rs = 1.0f / sqrtf(sq * (1.0f / 128.0f) + 1e-5f);
    h[r * DM + lane]      = g[lane]      * d0 * rs + bta[lane];
    h[r * DM + lane + 64] = g[lane + 64] * d1 * rs + bta[lane + 64];
  }
}

// 2-layer post-LN transformer encoder on a thread subset [0,nth).
// SINGLE call site for both halves -> __syncthreads sequence is uniform across the WG.
// Attention head-chunked (4 heads/chunk); FF column-chunked (256 cols/chunk, FF2 accumulated).
// Scratch: q,k,v (T*128 each) + s (4*T*T)  |  FF reuses: hidden T*256 at scr, ff2out at scr+T*256.
__device__ void encode_block(float* __restrict__ h, float* __restrict__ scr,
                             const float* __restrict__ tok, int T,
                             const float* __restrict__ embW, const float* __restrict__ embB,
                             const float* __restrict__ attnW, const float* __restrict__ attnB,
                             const float* __restrict__ W1, const float* __restrict__ b1,
                             const float* __restrict__ W2, const float* __restrict__ b2,
                             const float* __restrict__ ln, int tid, int nth)
{
  const int lane = tid & 63;
  const int wvl = tid >> 6;
  const int nwv = nth >> 6;
  // embedding: h = tok(Tx2) @ embW(2x128) + embB
  for (int idx = tid; idx < T * DM; idx += nth) {
    int r = idx >> 7, c = idx & 127;
    h[idx] = tok[2 * r] * embW[c] + tok[2 * r + 1] * embW[DM + c] + embB[c];
  }
  __syncthreads();
  float* q = scr;
  float* k = scr + T * DM;
  float* v = scr + 2 * T * DM;
  float* s = scr + 3 * T * DM;   // 4*T*T (one head-chunk)
  const int TT = T * T;
  for (int l = 0; l < 2; ++l) {
    const float* Wq = attnW + (size_t)(l * 4 + 0) * DM * DM;
    const float* Wk = attnW + (size_t)(l * 4 + 1) * DM * DM;
    const float* Wv = attnW + (size_t)(l * 4 + 2) * DM * DM;
    const float* Wo = attnW + (size_t)(l * 4 + 3) * DM * DM;
    const float* bq = attnB + (l * 4 + 0) * DM;
    const float* bk = attnB + (l * 4 + 1) * DM;
    const float* bv = attnB + (l * 4 + 2) * DM;
    const float* bo = attnB + (l * 4 + 3) * DM;
    matmul_rt<2,128,128>(h, DM, Wq, DM, bq, q, DM, T, false, false, tid, nth);
    matmul_rt<2,128,128>(h, DM, Wk, DM, bk, k, DM, T, false, false, tid, nth);
    matmul_rt<2,128,128>(h, DM, Wv, DM, bv, v, DM, T, false, false, tid, nth);
    __syncthreads();
    for (int ch = 0; ch < 2; ++ch) {
      // scores for heads ch*4 .. ch*4+3
      for (int idx = tid; idx < 4 * TT; idx += nth) {
        int hd4 = idx / TT; int rem = idx - hd4 * TT; int i = rem / T; int j = rem - i * T;
        int hd = ch * 4 + hd4;
        const float4* q4 = (const float4*)(q + i * DM + hd * HDM);
        const float4* k4 = (const float4*)(k + j * DM + hd * HDM);
        float acc = 0.f;
#pragma unroll
        for (int d = 0; d < 4; ++d) {
          float4 qa = q4[d], ka = k4[d];
          acc += qa.x * ka.x + qa.y * ka.y + qa.z * ka.z + qa.w * ka.w;
        }
        s[idx] = acc * 0.25f;
      }
      __syncthreads();
      // row softmax over 4*T rows
      for (int r = wvl; r < 4 * T; r += nwv) {
        float val = (lane < T) ? s[r * T + lane] : -INFINITY;
        float mx = val;
        for (int off = 32; off; off >>= 1) mx = fmaxf(mx, __shfl_xor(mx, off));
        float e = (lane < T) ? expf(val - mx) : 0.f;
        float sum = e;
        for (int off = 32; off; off >>= 1) sum += __shfl_xor(sum, off);
        if (lane < T) s[r * T + lane] = e / sum;
      }
      __syncthreads();
      // attention output for this chunk's 64 columns, written into q (those q cols are dead)
      for (int idx = tid; idx < T * 64; idx += nth) {
        int i = idx >> 6; int cc = idx & 63; int col = ch * 64 + cc; int hd4 = cc >> 4;
        const float* ar = s + (hd4 * T + i) * T;
        float acc = 0.f;
#pragma unroll 4
        for (int j = 0; j < T; ++j) acc = fmaf(ar[j], v[j * DM + col], acc);
        q[i * DM + col] = acc;
      }
      __syncthreads();
    }
    // output projection into k, then h = LN(h + proj)
    matmul_rt<2,128,128>(q, DM, Wo, DM, bo, k, DM, T, false, false, tid, nth);
    __syncthreads();
    layernorm_add(h, k, ln + ((l * 2 + 0) * 2 + 0) * DM, ln + ((l * 2 + 0) * 2 + 1) * DM, T, tid, nth);
    __syncthreads();
    // FF, column-chunked: hidden_ch = relu(h @ W1[:,ch*256:+256]); ff2out (+)= hidden_ch @ W2[ch*256:+256,:]
    const float* W1l = W1 + (size_t)l * DM * FFDIM;
    const float* b1l = b1 + l * FFDIM;
    const float* W2l = W2 + (size_t)l * FFDIM * DM;
    float* hidden = scr;             // T*256 (overlaps q,k - dead)
    float* ff2out = scr + T * 256;   // T*128 (overlaps v - dead)
    for (int ch = 0; ch < 2; ++ch) {
      matmul_rt<4,256,128>(h, DM, W1l + ch * 256, FFDIM, b1l + ch * 256, hidden, 256, T, true, false, tid, nth);
      __syncthreads();
      matmul_rt<2,128,256>(hidden, 256, W2l + (size_t)ch * 256 * DM, DM, b2 + l * DM,
                           ff2out, DM, T, false, (ch == 1), tid, nth);
      __syncthreads();
    }
    layernorm_add(h, ff2out, ln + ((l * 2 + 1) * 2 + 0) * DM, ln + ((l * 2 + 1) * 2 + 1) * DM, T, tid, nth);
    __syncthreads();
  }
}

__global__ __launch_bounds__(NT)
void tsp_kernel(Params p)
{
  const int b = blockIdx.x;
  const int tid = threadIdx.x;
  const int lane = tid & 63;
  const int wv = tid >> 6;

  extern __shared__ float sm[];
  float* hA   = sm + OFF_HA;
  float* scrA = sm + OFF_SCRA;
  float* hS   = sm + OFF_HS;
  float* scrS = sm + OFF_SCRS;

  __shared__ float xl[NN * 2];
  __shared__ int   maskS[NN];
  __shared__ int   knnS[KS];
  __shared__ int   validS[KA];
  __shared__ float d2S[NN];
  __shared__ float tokA[TA * 2];
  __shared__ float tokS[TS * 2];
  __shared__ int   lastS;
  __shared__ float logpS;

  // per-thread half assignment: waves 0-3 -> encoder A (256 thr), waves 4-15 -> encoder S (768 thr)
  const int half = (tid >= 256) ? 1 : 0;
  const int tl   = half ? tid - 256 : tid;
  const int nth  = half ? 768 : 256;
  float* hX   = half ? hS : hA;
  float* scrX = half ? scrS : scrA;
  const float* tokX = half ? tokS : tokA;
  const int TX = half ? TS : TA;
  const float* eW  = half ? p.s_emb_W  : p.a_emb_W;
  const float* eB  = half ? p.s_emb_b  : p.a_emb_b;
  const float* aW  = half ? p.s_attn_W : p.a_attn_W;
  const float* aB  = half ? p.s_attn_b : p.a_attn_b;
  const float* fW1 = half ? p.s_ff_W1  : p.a_ff_W1;
  const float* fb1 = half ? p.s_ff_b1  : p.a_ff_b1;
  const float* fW2 = half ? p.s_ff_W2  : p.a_ff_W2;
  const float* fb2 = half ? p.s_ff_b2  : p.a_ff_b2;
  const float* lnX = half ? p.s_ln     : p.a_ln;

  // ---- init ----
  for (int i = tid; i < NN * 2; i += NT) xl[i] = p.x[b * NN * 2 + i];
  const int st = p.start[b];
  for (int i = tid; i < NN; i += NT) maskS[i] = (i != st) ? 1 : 0;
  if (tid == 0) {
    lastS = st; logpS = 0.f;
    p.out[b * NN] = (float)st;
  }
  __syncthreads();
  const float fx = xl[2 * st], fy = xl[2 * st + 1];

  for (int t = 0; t < NN - 1; ++t) {
    const int last = lastS;
    const float lx = xl[2 * last], ly = xl[2 * last + 1];

    // ---- squared distances, masked -> BIG (no FMA contraction: match np bit-exact) ----
    for (int j = tid; j < NN; j += NT) {
      float dx = __fsub_rn(xl[2 * j], lx);
      float dy = __fsub_rn(xl[2 * j + 1], ly);
      float dd = __fadd_rn(__fmul_rn(dx, dx), __fmul_rn(dy, dy));
      d2S[j] = maskS[j] ? dd : BIGF;
    }
    __syncthreads();

    // ---- stable top-KS (ascending d2, ties -> lowest index), wave 0 ----
    if (wv == 0) {
      float v = (lane < NN) ? d2S[lane] : 2.0f * BIGF;
      const int vi = lane;
      for (int s2 = 0; s2 < KS; ++s2) {
        float mv = v; int mi = vi;
        for (int off = 32; off; off >>= 1) {
          float ov = __shfl_xor(mv, off);
          int oi = __shfl_xor(mi, off);
          if (ov < mv || (ov == mv && oi < mi)) { mv = ov; mi = oi; }
        }
        if (lane == 0) knnS[s2] = mi;
        if (vi == mi) v = 4.0f * BIGF;  // remove winner
      }
    }
    __syncthreads();

    // ---- valid flags + tokens ----
    if (tid < KA) validS[tid] = maskS[knnS[tid]];
    if (tid < KS) { int j = knnS[tid]; tokS[2 * tid] = xl[2 * j]; tokS[2 * tid + 1] = xl[2 * j + 1]; }
    if (tid < KA) { int j = knnS[tid]; tokA[2 * tid] = xl[2 * j]; tokA[2 * tid + 1] = xl[2 * j + 1]; }
    if (tid == NT - 1) { tokA[2 * KA] = lx; tokA[2 * KA + 1] = ly; }
    if (tid == NT - 2) { tokS[2 * KS] = lx; tokS[2 * KS + 1] = ly; }
    if (tid == NT - 3) { tokS[2 * KS + 2] = fx; tokS[2 * KS + 3] = fy; }
    __syncthreads();

    // ---- both encoders concurrently (uniform call site -> aligned barriers) ----
    encode_block(hX, scrX, tokX, TX, eW, eB, aW, aB, fW1, fb1, fW2, fb2, lnX, tl, nth);
    // hA = enc_A output (rows 0..15), hS = enc_S output (rows 0..36); both persist.

    // ---- decoder scratch inside scrS (encS scratch dead) ----
    float* embq = scrS;            // 384
    float* embo = scrS + 384;      // 15 x 256
    float* Kd   = scrS + 4224;     // 15 x 256
    float* Vd   = scrS + 8064;     // 15 x 256
    float* hdec = scrS + 11904;    // 128
    float* qd   = scrS + 12032;    // 128
    float* scd  = scrS + 12160;    // 8 x 15 = 120
    float* od   = scrS + 12288;    // 128
    float* tmp  = scrS + 12416;    // 128
    float* red  = scrS + 12544;    // 1024

    if (tid < 384) {
      embq[tid] = (tid < 128) ? hA[KA * DM + tid]
                : (tid < 256) ? hS[KS * DM + (tid - 128)]
                              : hS[(KS + 1) * DM + (tid - 256)];
    }
    for (int idx = tid; idx < KA * 256; idx += NT) {
      int r = idx >> 8, c = idx & 255;
      embo[idx] = (c < 128) ? hA[r * DM + c] : hS[r * DM + (c - 128)];
    }
    __syncthreads();

    matmul_rt<1,256,256>(embo, 256, p.WK, 256, p.bK, Kd, 256, KA, false, false, tid, NT);
    matmul_rt<1,256,256>(embo, 256, p.WV, 256, p.bV, Vd, 256, KA, false, false, tid, NT);
    matvec128(embq, p.Wq_mlp, p.bq_mlp, hdec, 384, red, tid);  // internal syncs order KV too

    // ---- decoder layer 0 (cross-attention) ----
    matvec128(hdec, p.d_Wq, p.d_bq, qd, DM, red, tid);
    if (tid < NHD * KA) {   // 120 threads
      int hd = tid / KA, kk2 = tid - hd * KA;
      const float* qh = qd + hd * HDM;
      const float* kh = Kd + kk2 * 256 + hd * HDM;
      float acc = 0.f;
#pragma unroll
      for (int d = 0; d < HDM; ++d) acc += qh[d] * kh[d];
      acc = acc / 4.0f;
      scd[tid] = validS[kk2] ? acc : -BIGF;
    }
    __syncthreads();
    if (tid < NHD) {
      float mx = -INFINITY;
#pragma unroll
      for (int kk2 = 0; kk2 < KA; ++kk2) mx = fmaxf(mx, scd[tid * KA + kk2]);
      float e[KA]; float sum = 0.f;
#pragma unroll
      for (int kk2 = 0; kk2 < KA; ++kk2) { e[kk2] = expf(scd[tid * KA + kk2] - mx); sum += e[kk2]; }
      float inv = 1.0f / sum;
#pragma unroll
      for (int kk2 = 0; kk2 < KA; ++kk2) scd[tid * KA + kk2] = e[kk2] * inv;
    }
    __syncthreads();
    if (tid < DM) {
      int hd = tid >> 4;
      float acc = 0.f;
#pragma unroll
      for (int kk2 = 0; kk2 < KA; ++kk2) acc = fmaf(scd[hd * KA + kk2], Vd[kk2 * 256 + tid], acc);
      od[tid] = acc;
    }
    __syncthreads();
    matvec128(od, p.d_Wo, p.d_bo, tmp, DM, red, tid);
    if (tid < DM) hdec[tid] += tmp[tid];
    __syncthreads();

    // ---- final pointer logits ----
    matvec128(hdec, p.d_Wq + DM * DM, p.d_bq + DM, qd, DM, red, tid);
    if (wv == 0) {
      float lg = -BIGF;
      if (lane < KA) {
        const float* kf = Kd + lane * 256 + 128;  // K[:, :, 1]
        float acc = 0.f;
#pragma unroll 8
        for (int d = 0; d < DM; ++d) acc = fmaf(qd[d], kf[d], acc);
        acc = acc / 11.313708498984761f;  // sqrt(128)
        lg = validS[lane] ? 10.0f * tanhf(acc) : -BIGF;
      }
      // argmax, ties -> lowest index (== argmax of softmax probs)
      float mv = lg; int mi = (lane < KA) ? lane : 1000;
      for (int off = 32; off; off >>= 1) {
        float ov = __shfl_xor(mv, off);
        int oi = __shfl_xor(mi, off);
        if (ov > mv || (ov == mv && oi < mi)) { mv = ov; mi = oi; }
      }
      float e = (lane < KA) ? expf(lg - mv) : 0.f;
      float sum = e;
      for (int off = 32; off; off >>= 1) sum += __shfl_xor(sum, off);
      if (lane == 0) {
        int nxt = knnS[mi];
        logpS += -logf(sum);  // lg[mi] - mv == 0
        maskS[nxt] = 0;
        lastS = nxt;
        p.out[b * NN + t + 1] = (float)nxt;
      }
    }
    __syncthreads();
  }

  if (tid == 0) p.out[NB * NN + b] = logpS;
}

} // namespace

extern "C" void kernel_launch(void* const* d_in, const int* in_sizes, int n_in,
                              void* d_out, int out_size, void* d_ws, size_t ws_size,
                              hipStream_t stream)
{
  (void)in_sizes; (void)n_in; (void)out_size; (void)d_ws; (void)ws_size;
  Params p;
  p.x        = (const float*)d_in[0];
  p.start    = (const int*)d_in[1];
  // d_in[2]=action_k (15), d_in[3]=state_k (35): fixed by problem, hardcoded.
  p.a_emb_W  = (const float*)d_in[4];
  p.a_emb_b  = (const float*)d_in[5];
  p.a_attn_W = (const float*)d_in[6];
  p.a_attn_b = (const float*)d_in[7];
  p.a_ff_W1  = (const float*)d_in[8];
  p.a_ff_b1  = (const float*)d_in[9];
  p.a_ff_W2  = (const float*)d_in[10];
  p.a_ff_b2  = (const float*)d_in[11];
  p.a_ln     = (const float*)d_in[12];
  p.s_emb_W  = (const float*)d_in[13];
  p.s_emb_b  = (const float*)d_in[14];
  p.s_attn_W = (const float*)d_in[15];
  p.s_attn_b = (const float*)d_in[16];
  p.s_ff_W1  = (const float*)d_in[17];
  p.s_ff_b1  = (const float*)d_in[18];
  p.s_ff_W2  = (const float*)d_in[19];
  p.s_ff_b2  = (const float*)d_in[20];
  p.s_ln     = (const float*)d_in[21];
  p.WK       = (const float*)d_in[22];
  p.bK       = (const float*)d_in[23];
  p.WV       = (const float*)d_in[24];
  p.bV       = (const float*)d_in[25];
  p.Wq_mlp   = (const float*)d_in[26];
  p.bq_mlp   = (const float*)d_in[27];
  p.d_Wq     = (const float*)d_in[28];
  p.d_bq     = (const float*)d_in[29];
  p.d_Wo     = (const float*)d_in[30];
  p.d_bo     = (const float*)d_in[31];
  p.out      = (float*)d_out;

  (void)hipFuncSetAttribute((const void*)tsp_kernel,
                            hipFuncAttributeMaxDynamicSharedMemorySize, SMEM_BYTES);
  tsp_kernel<<<NB, NT, SMEM_BYTES, stream>>>(p);
}